// Round 17
// baseline (229.012 us; speedup 1.0000x reference)
//
#include <hip/hip_runtime.h>
#include <hip/hip_bf16.h>

using bf16 = __hip_bfloat16;
typedef __attribute__((ext_vector_type(8))) short short8;   // 8 bf16 (K=32 MFMA A/B frag)
typedef __attribute__((ext_vector_type(4))) short short4v;  // 4 bf16 (K=16 MFMA A/B frag)
typedef __attribute__((ext_vector_type(4))) float f32x4;    // MFMA C/D frag

#define MFMA16(a, b, c) __builtin_amdgcn_mfma_f32_16x16x32_bf16((a), (b), (c), 0, 0, 0)
// K=16 bf16 MFMA (gfx90a+ "_1k" variant, carried on gfx950 per ISA §10)
#define MFMA16K16(a, b, c) __builtin_amdgcn_mfma_f32_16x16x16bf16_1k((a), (b), (c), 0, 0, 0)

__device__ inline void async16(bf16* lds, const bf16* g) {
  __builtin_amdgcn_global_load_lds(
      (const __attribute__((address_space(1))) void*)g,
      (__attribute__((address_space(3))) void*)lds, 16, 0, 0);
}

__device__ inline short bfs(float x) {
  union { bf16 h; short s; } u; u.h = __float2bfloat16(x); return u.s;
}
__device__ inline short4v pack4(float a, float b, float c, float d) {
  short4v r; r[0] = bfs(a); r[1] = bfs(b); r[2] = bfs(c); r[3] = bfs(d); return r;
}
// truncating bf16 pack (v_perm); bias cancels in O=num/den
__device__ inline short4v pack4t(float a, float b, float c, float d) {
  unsigned lo = __builtin_amdgcn_perm(__float_as_uint(b), __float_as_uint(a), 0x07060302u);
  unsigned hi = __builtin_amdgcn_perm(__float_as_uint(d), __float_as_uint(c), 0x07060302u);
  union { unsigned u[2]; short4v v; } r;
  r.u[0] = lo; r.u[1] = hi;
  return r.v;
}

// fused fp32->bf16 conversion for x + 4 weight matrices
__global__ __launch_bounds__(256) void cvt_all(
    const float* __restrict__ x,  const float* __restrict__ Wq,
    const float* __restrict__ Wk, const float* __restrict__ Wv,
    const float* __restrict__ Wo,
    bf16* __restrict__ xb, bf16* __restrict__ Wqb, bf16* __restrict__ Wkb,
    bf16* __restrict__ Wvb, bf16* __restrict__ Wob) {
  int i = blockIdx.x * 256 + threadIdx.x;
  const float* s; bf16* d; int off;
  if (i < 1048576)      { s = x;  d = xb;  off = i; }
  else if (i < 1310720) { s = Wq; d = Wqb; off = i - 1048576; }
  else if (i < 1572864) { s = Wk; d = Wkb; off = i - 1310720; }
  else if (i < 1835008) { s = Wv; d = Wvb; off = i - 1572864; }
  else                  { s = Wo; d = Wob; off = i - 1835008; }
  float4 v = ((const float4*)s)[off];
  short4v o = pack4(v.x, v.y, v.z, v.w);
  *(short4v*)&d[(size_t)off * 4] = o;
}

// Fused QKV GEMM -> Q/K [B,H,2048,64], V^T [B,H,64,2048]. grid (32, 24).
// BK=64 K-loop, XOR-swizzled staging (conflict-free b128 frag reads).
// Q pre-scaled by 0.125*asc[h]*log2e. V^T epilogue: LDS transpose -> b64.
__global__ __launch_bounds__(256) void gemm_qkv(
    const bf16* __restrict__ A,
    const bf16* __restrict__ Wq, const bf16* __restrict__ Wk, const bf16* __restrict__ Wv,
    const float* __restrict__ bq, const float* __restrict__ bk, const float* __restrict__ bv,
    const float* __restrict__ asc,
    bf16* __restrict__ Qb, bf16* __restrict__ Kb, bf16* __restrict__ Vtb) {
  __shared__ __align__(16) bf16 As[128 * 64];       // [row][chunk^(row&7)]
  __shared__ __align__(16) bf16 Bs[128 * 64];
  __shared__ __align__(16) bf16 scrT[4][16 * 72];   // V^T transpose scratch

  const int tid = threadIdx.x;
  const int lane = tid & 63;
  const int w = tid >> 6;
  const int m0 = blockIdx.x * 128;
  const int region = blockIdx.y >> 3;
  const int n0loc = (blockIdx.y & 7) * 128;
  const int wm = (w >> 1) * 64;
  const int wn = (w & 1) * 64;
  const int rq = lane & 15;
  const int quad = lane >> 4;

  const bf16* W = region == 0 ? Wq : (region == 1 ? Wk : Wv);
  const float* bias = region == 0 ? bq : (region == 1 ? bk : bv);
  bf16* C = region == 0 ? Qb : (region == 1 ? Kb : Vtb);

  f32x4 acc[4][4] = {};
  const bf16* Ag = A + (size_t)m0 * 1024;
  const bf16* Wg = W + (size_t)n0loc * 1024;

  const int srow = lane >> 3;                     // 0..7
  const int sws = ((lane & 7) ^ srow) * 8;        // swizzled src chunk offset
  const int c0 = (quad ^ (rq & 7)) * 8;           // frag retrieval (kstep 0)

  for (int k0 = 0; k0 < 1024; k0 += 64) {
    __syncthreads();
#pragma unroll
    for (int t = 0; t < 4; ++t) {
      int rb = w * 32 + t * 8;
      int row = rb + srow;
      async16(&As[rb * 64 + lane * 8], Ag + (size_t)row * 1024 + k0 + sws);
      async16(&Bs[rb * 64 + lane * 8], Wg + (size_t)row * 1024 + k0 + sws);
    }
    __syncthreads();

#pragma unroll
    for (int ks = 0; ks < 2; ++ks) {
      int off = c0 ^ (ks * 32);
      short8 a[4], b[4];
#pragma unroll
      for (int i = 0; i < 4; ++i) a[i] = *(const short8*)&As[(wm + i * 16 + rq) * 64 + off];
#pragma unroll
      for (int j = 0; j < 4; ++j) b[j] = *(const short8*)&Bs[(wn + j * 16 + rq) * 64 + off];
#pragma unroll
      for (int i = 0; i < 4; ++i)
#pragma unroll
        for (int j = 0; j < 4; ++j) acc[i][j] = MFMA16(a[i], b[j], acc[i][j]);
    }
  }

  const float LOG2E = 1.44269504088896f;
  if (region < 2) {
#pragma unroll
    for (int i = 0; i < 4; ++i)
#pragma unroll
      for (int j = 0; j < 4; ++j)
#pragma unroll
        for (int r2 = 0; r2 < 4; ++r2) {
          int m = m0 + wm + i * 16 + quad * 4 + r2;
          int nr = n0loc + wn + j * 16 + rq;
          int bb = m >> 11, t = m & 2047, h = nr >> 6, hd = nr & 63;
          float v = acc[i][j][r2] + bias[nr];
          if (region == 0) v *= 0.125f * asc[h] * LOG2E;
          C[(((size_t)(bb * 16 + h)) * 2048 + t) * 64 + hd] = __float2bfloat16(v);
        }
  } else {
    // V^T: per-wave transpose -> coalesced b64 stores along t
    const int bb = m0 >> 11;
    const int h = (n0loc + wn) >> 6;
    const int tbase = (m0 & 2047) + wm;
    bf16* scr = scrT[w];
#pragma unroll
    for (int j = 0; j < 4; ++j) {
      int nr = n0loc + wn + j * 16 + rq;
      float bi = bias[nr];
#pragma unroll
      for (int i = 0; i < 4; ++i) {
        short4v pv = pack4(acc[i][j][0] + bi, acc[i][j][1] + bi,
                           acc[i][j][2] + bi, acc[i][j][3] + bi);
        *(short4v*)&scr[rq * 72 + i * 16 + quad * 4] = pv;   // [dim16=rq][t64]
      }
#pragma unroll
      for (int pp = 0; pp < 4; ++pp) {
        int hdl = pp * 4 + quad;
        short4v v4 = *(const short4v*)&scr[hdl * 72 + rq * 4];
        size_t addr = (((size_t)(bb * 16 + h)) * 64 + j * 16 + hdl) * 2048 + tbase + rq * 4;
        *(short4v*)&C[addr] = v4;
      }
    }
  }
}

// Out-proj GEMM + bias + residual (fp32 out). 64x128 tile, grid (64,8).
__global__ __launch_bounds__(256) void gemm_out(
    const bf16* __restrict__ A, const bf16* __restrict__ W,
    const float* __restrict__ bias, const float* __restrict__ R,
    float* __restrict__ Y) {
  __shared__ __align__(16) bf16 As[64 * 64];
  __shared__ __align__(16) bf16 Bs[128 * 64];

  const int tid = threadIdx.x;
  const int lane = tid & 63;
  const int w = tid >> 6;
  const int m0 = blockIdx.x * 64;
  const int n0 = blockIdx.y * 128;
  const int wm = (w >> 1) * 32;
  const int wn = (w & 1) * 64;
  const int rq = lane & 15;
  const int quad = lane >> 4;

  f32x4 acc[2][4] = {};
  const bf16* Ag = A + (size_t)m0 * 1024;
  const bf16* Wg = W + (size_t)n0 * 1024;

  const int srow = lane >> 3;
  const int sws = ((lane & 7) ^ srow) * 8;
  const int c0 = (quad ^ (rq & 7)) * 8;

  for (int k0 = 0; k0 < 1024; k0 += 64) {
    __syncthreads();
#pragma unroll
    for (int t = 0; t < 2; ++t) {
      int rb = w * 16 + t * 8;
      int row = rb + srow;
      async16(&As[rb * 64 + lane * 8], Ag + (size_t)row * 1024 + k0 + sws);
    }
#pragma unroll
    for (int t = 0; t < 4; ++t) {
      int rb = w * 32 + t * 8;
      int row = rb + srow;
      async16(&Bs[rb * 64 + lane * 8], Wg + (size_t)row * 1024 + k0 + sws);
    }
    __syncthreads();

#pragma unroll
    for (int ks = 0; ks < 2; ++ks) {
      int off = c0 ^ (ks * 32);
      short8 a[2], b[4];
#pragma unroll
      for (int i = 0; i < 2; ++i) a[i] = *(const short8*)&As[(wm + i * 16 + rq) * 64 + off];
#pragma unroll
      for (int j = 0; j < 4; ++j) b[j] = *(const short8*)&Bs[(wn + j * 16 + rq) * 64 + off];
#pragma unroll
      for (int i = 0; i < 2; ++i)
#pragma unroll
        for (int j = 0; j < 4; ++j) acc[i][j] = MFMA16(a[i], b[j], acc[i][j]);
    }
  }

#pragma unroll
  for (int i = 0; i < 2; ++i)
#pragma unroll
    for (int j = 0; j < 4; ++j)
#pragma unroll
      for (int r2 = 0; r2 < 4; ++r2) {
        int m = m0 + wm + i * 16 + quad * 4 + r2;
        int n = n0 + wn + j * 16 + rq;
        Y[(size_t)m * 1024 + n] = acc[i][j][r2] + bias[n] + R[(size_t)m * 1024 + n];
      }
}

// Flash attention v12: S^T formulation — NO P LDS round-trip.
// S^T = K·Q^T via 16x16x32 (A=K, B=Q): C-layout col=q, row=key=quad*4+r,
// which IS the B-operand layout of 16x16x16 MFMA. P^T goes register->register
// (exp2 + v_perm pack) into PV: O^T[d][q] += V^T-frag x P^T-frag (K=16).
// l via ones-A MFMA. LDS = Ks+Vs only (16 KB). 64 q-rows/wave, K-split x2,
// linear partial combine (max-free exp2 softmax, Q pre-scaled to log2 domain).
__global__ __launch_bounds__(256, 2) void attn_kernel(
    const bf16* __restrict__ Qb, const bf16* __restrict__ Kb,
    const bf16* __restrict__ Vtb,
    bf16* __restrict__ P0, bf16* __restrict__ P1, float* __restrict__ lbuf) {
  __shared__ __align__(16) bf16 Ks[64 * 64];      // [key][chunk^(key&7)]
  __shared__ __align__(16) bf16 Vs[64 * 64];      // [d][chunk^(d&7)]

  const int q0 = blockIdx.x * 256;
  const int h = blockIdx.y;
  const int b = blockIdx.z & 1;
  const int half = blockIdx.z >> 1;
  const int tid = threadIdx.x;
  const int lane = tid & 63;
  const int w = tid >> 6;
  const int rq = lane & 15;
  const int quad = lane >> 4;
  const int kq = quad * 8;

  const size_t head = ((size_t)(b * 16 + h)) * 2048 * 64;
  const bf16* Qh = Qb + head;
  const bf16* Kh = Kb + head;
  const bf16* Vh = Vtb + head;   // [64][2048]

  // Q B-frags (B[k=d][n=q]): same register layout as before
  short8 aq[4][2];
#pragma unroll
  for (int s = 0; s < 4; ++s) {
    const bf16* qrow = Qh + (size_t)(q0 + w * 64 + s * 16 + rq) * 64;
    aq[s][0] = *(const short8*)&qrow[kq];
    aq[s][1] = *(const short8*)&qrow[kq + 32];
  }

  short4v ones4;
#pragma unroll
  for (int i = 0; i < 4; ++i) ones4[i] = (short)0x3F80;   // bf16 1.0

  const int srow = lane >> 3;
  const int sws = ((lane & 7) ^ srow) * 8;        // staging swizzle (g=row&7)
  const int c0 = (quad ^ (rq & 7)) * 8;           // b128 frag retrieval
  const int c1 = c0 ^ 32;

  f32x4 accO[4][4] = {};   // [s][dt] : D[m=d=quad*4+r][n=q=rq]
  f32x4 lacc[4] = {};

  const int kt0 = half * 16;
  for (int kt = kt0; kt < kt0 + 16; ++kt) {
    __syncthreads();
#pragma unroll
    for (int t = 0; t < 2; ++t) {
      int rb = w * 16 + t * 8;
      int row = rb + srow;
      async16(&Ks[rb * 64 + lane * 8], Kh + (size_t)(kt * 64 + row) * 64 + sws);
      async16(&Vs[rb * 64 + lane * 8], Vh + (size_t)row * 2048 + kt * 64 + sws);
    }
    __syncthreads();

    // K A-frags (A[m=key][k=d]): natural rows j*16+rq, conflict-free b128
    short8 bkA[4][2];
#pragma unroll
    for (int j = 0; j < 4; ++j) {
      const bf16* kr = &Ks[(j * 16 + rq) * 64];
      bkA[j][0] = *(const short8*)&kr[c0];
      bkA[j][1] = *(const short8*)&kr[c1];
    }
    // V A-frags for K=16 PV (A[m=d][k=key_local=quad*4+i]): b64 reads
    short4v av[4][4];   // [dt][j]
#pragma unroll
    for (int dt = 0; dt < 4; ++dt) {
      const bf16* vr = &Vs[(dt * 16 + rq) * 64];
#pragma unroll
      for (int j = 0; j < 4; ++j) {
        int cch = 2 * j + (quad >> 1);            // logical 8-chunk of key j*16+quad*4
        av[dt][j] = *(const short4v*)&vr[((cch ^ (rq & 7)) * 8) + (quad & 1) * 4];
      }
    }

#pragma unroll
    for (int s = 0; s < 4; ++s) {
      // S^T tiles: keys j*16+quad*4+r, q = s-tile + rq (Q pre-scaled, log2)
      f32x4 ST[4] = {};
#pragma unroll
      for (int j = 0; j < 4; ++j) {
        ST[j] = MFMA16(bkA[j][0], aq[s][0], ST[j]);
        ST[j] = MFMA16(bkA[j][1], aq[s][1], ST[j]);
      }
      // P^T B-frags: exp2 + truncating pack, register-only
      short4v bp[4];
#pragma unroll
      for (int j = 0; j < 4; ++j)
        bp[j] = pack4t(exp2f(ST[j][0]), exp2f(ST[j][1]),
                       exp2f(ST[j][2]), exp2f(ST[j][3]));
      // O^T += V^T x P^T ; l += 1 x P^T
#pragma unroll
      for (int dt = 0; dt < 4; ++dt)
#pragma unroll
        for (int j = 0; j < 4; ++j)
          accO[s][dt] = MFMA16K16(av[dt][j], bp[j], accO[s][dt]);
#pragma unroll
      for (int j = 0; j < 4; ++j)
        lacc[s] = MFMA16K16(ones4, bp[j], lacc[s]);
    }
  }

  // epilogue: UNNORMALIZED partial O (bf16, b64 stores: 4 contiguous d) + l
  bf16* Pout = half ? P1 : P0;
  float* lout = lbuf + half * 65536;
#pragma unroll
  for (int s = 0; s < 4; ++s) {
    int t = q0 + w * 64 + s * 16 + rq;
#pragma unroll
    for (int dt = 0; dt < 4; ++dt) {
      short4v ov = pack4(accO[s][dt][0], accO[s][dt][1],
                         accO[s][dt][2], accO[s][dt][3]);
      *(short4v*)&Pout[((size_t)(b * 2048 + t)) * 1024 + h * 64 + dt * 16 + quad * 4] = ov;
    }
    if (quad == 0) lout[(b * 16 + h) * 2048 + t] = lacc[s][0];
  }
}

// Combine K-split partials: attn = (P0 + P1) / (l0 + l1)   (in-place over P0)
__global__ __launch_bounds__(256) void combine_kernel(
    bf16* __restrict__ P0, const bf16* __restrict__ P1,
    const float* __restrict__ lbuf) {
  const int row = blockIdx.x;
  const int tid = threadIdx.x;
  const int col = tid * 4;
  const int b = row >> 11, t = row & 2047;
  const int h = col >> 6;
  const float l = lbuf[(b * 16 + h) * 2048 + t] + lbuf[65536 + (b * 16 + h) * 2048 + t];
  const float rl = 1.f / l;
  size_t base = (size_t)row * 1024 + col;
  short4v p0 = *(const short4v*)&P0[base];
  short4v p1 = *(const short4v*)&P1[base];
  union { short s; bf16 h; } u;
  float v[4];
#pragma unroll
  for (int i = 0; i < 4; ++i) {
    u.s = p0[i]; float a = __bfloat162float(u.h);
    u.s = p1[i]; float c = __bfloat162float(u.h);
    v[i] = (a + c) * rl;
  }
  *(short4v*)&P0[base] = pack4(v[0], v[1], v[2], v[3]);
}

// LayerNorm over D=1024 per row; all fp32
__global__ __launch_bounds__(256) void ln_kernel(
    const float* __restrict__ Y, const float* __restrict__ gamma,
    const float* __restrict__ beta, float* __restrict__ out) {
  const int row = blockIdx.x;
  const int tid = threadIdx.x;
  const int lane = tid & 63;
  const int w = tid >> 6;
  const float* y = Y + (size_t)row * 1024;

  float4 v = *(const float4*)&y[tid * 4];
  float s = v.x + v.y + v.z + v.w;
  float ss = v.x * v.x + v.y * v.y + v.z * v.z + v.w * v.w;
#pragma unroll
  for (int msk = 1; msk < 64; msk <<= 1) {
    s += __shfl_xor(s, msk);
    ss += __shfl_xor(ss, msk);
  }
  __shared__ float red[2][4];
  if (lane == 0) { red[0][w] = s; red[1][w] = ss; }
  __syncthreads();
  s = red[0][0] + red[0][1] + red[0][2] + red[0][3];
  ss = red[1][0] + red[1][1] + red[1][2] + red[1][3];
  float mean = s * (1.f / 1024.f);
  float var = ss * (1.f / 1024.f) - mean * mean;
  float rstd = rsqrtf(var + 1e-5f);
  float4 g = *(const float4*)&gamma[tid * 4];
  float4 bt = *(const float4*)&beta[tid * 4];
  float4 o;
  o.x = (v.x - mean) * rstd * g.x + bt.x;
  o.y = (v.y - mean) * rstd * g.y + bt.y;
  o.z = (v.z - mean) * rstd * g.z + bt.z;
  o.w = (v.w - mean) * rstd * g.w + bt.w;
  *(float4*)&out[(size_t)row * 1024 + tid * 4] = o;
}

extern "C" void kernel_launch(void* const* d_in, const int* in_sizes, int n_in,
                              void* d_out, int out_size, void* d_ws, size_t ws_size,
                              hipStream_t stream) {
  const float* x     = (const float*)d_in[0];
  const float* asc   = (const float*)d_in[1];
  const float* Wq    = (const float*)d_in[2];
  const float* bq    = (const float*)d_in[3];
  const float* Wk    = (const float*)d_in[4];
  const float* bk    = (const float*)d_in[5];
  const float* Wv    = (const float*)d_in[6];
  const float* bv    = (const float*)d_in[7];
  const float* Wo    = (const float*)d_in[8];
  const float* bo    = (const float*)d_in[9];
  const float* gamma = (const float*)d_in[10];
  const float* beta  = (const float*)d_in[11];
  float* out = (float*)d_out;

  char* ws = (char*)d_ws;
  const size_t MB = 1024 * 1024;
  bf16* Qb   = (bf16*)(ws);
  bf16* Kb   = (bf16*)(ws + 8 * MB);
  bf16* Vtb  = (bf16*)(ws + 16 * MB);
  bf16* attn = (bf16*)(ws + 24 * MB);   // P0
  bf16* xb   = (bf16*)(ws + 32 * MB);   // P1 after gemm_qkv
  bf16* Wqb  = (bf16*)(ws + 40 * MB);   // lbuf after gemm_qkv
  bf16* Wkb  = (bf16*)(ws + 42 * MB);
  bf16* Wvb  = (bf16*)(ws + 44 * MB);
  bf16* Wob  = (bf16*)(ws + 46 * MB);
  float* y   = (float*)(ws);            // 16 MiB over dead Qb+Kb
  bf16* P1   = xb;
  float* lbuf = (float*)Wqb;

  cvt_all<<<dim3(8192), dim3(256), 0, stream>>>(x, Wq, Wk, Wv, Wo, xb, Wqb, Wkb, Wvb, Wob);
  gemm_qkv<<<dim3(32, 24), dim3(256), 0, stream>>>(xb, Wqb, Wkb, Wvb, bq, bk, bv, asc, Qb, Kb, Vtb);
  attn_kernel<<<dim3(8, 16, 4), dim3(256), 0, stream>>>(Qb, Kb, Vtb, attn, P1, lbuf);
  combine_kernel<<<dim3(4096), dim3(256), 0, stream>>>(attn, P1, lbuf);
  gemm_out<<<dim3(64, 8), dim3(256), 0, stream>>>(attn, Wob, bo, x, y);
  ln_kernel<<<dim3(4096), dim3(256), 0, stream>>>(y, gamma, beta, out);
}

// Round 18
// 223.795 us; speedup vs baseline: 1.0233x; 1.0233x over previous
//
#include <hip/hip_runtime.h>
#include <hip/hip_bf16.h>

using bf16 = __hip_bfloat16;
typedef __attribute__((ext_vector_type(8))) short short8;   // 8 bf16 (MFMA A/B frag)
typedef __attribute__((ext_vector_type(4))) short short4v;  // 4 bf16 = b64
typedef __attribute__((ext_vector_type(4))) float f32x4;    // MFMA C/D frag

#define MFMA16(a, b, c) __builtin_amdgcn_mfma_f32_16x16x32_bf16((a), (b), (c), 0, 0, 0)

__device__ inline void async16(bf16* lds, const bf16* g) {
  __builtin_amdgcn_global_load_lds(
      (const __attribute__((address_space(1))) void*)g,
      (__attribute__((address_space(3))) void*)lds, 16, 0, 0);
}

__device__ inline short bfs(float x) {
  union { bf16 h; short s; } u; u.h = __float2bfloat16(x); return u.s;
}
__device__ inline short4v pack4(float a, float b, float c, float d) {
  short4v r; r[0] = bfs(a); r[1] = bfs(b); r[2] = bfs(c); r[3] = bfs(d); return r;
}
// truncating bf16 pack (v_perm); bias cancels in O=num/den
__device__ inline short4v pack4t(float a, float b, float c, float d) {
  unsigned lo = __builtin_amdgcn_perm(__float_as_uint(b), __float_as_uint(a), 0x07060302u);
  unsigned hi = __builtin_amdgcn_perm(__float_as_uint(d), __float_as_uint(c), 0x07060302u);
  union { unsigned u[2]; short4v v; } r;
  r.u[0] = lo; r.u[1] = hi;
  return r.v;
}

// fused fp32->bf16 conversion for x + 4 weight matrices
__global__ __launch_bounds__(256) void cvt_all(
    const float* __restrict__ x,  const float* __restrict__ Wq,
    const float* __restrict__ Wk, const float* __restrict__ Wv,
    const float* __restrict__ Wo,
    bf16* __restrict__ xb, bf16* __restrict__ Wqb, bf16* __restrict__ Wkb,
    bf16* __restrict__ Wvb, bf16* __restrict__ Wob) {
  int i = blockIdx.x * 256 + threadIdx.x;
  const float* s; bf16* d; int off;
  if (i < 1048576)      { s = x;  d = xb;  off = i; }
  else if (i < 1310720) { s = Wq; d = Wqb; off = i - 1048576; }
  else if (i < 1572864) { s = Wk; d = Wkb; off = i - 1310720; }
  else if (i < 1835008) { s = Wv; d = Wvb; off = i - 1572864; }
  else                  { s = Wo; d = Wob; off = i - 1835008; }
  float4 v = ((const float4*)s)[off];
  short4v o = pack4(v.x, v.y, v.z, v.w);
  *(short4v*)&d[(size_t)off * 4] = o;
}

// Fused QKV GEMM -> Q/K [B,H,2048,64], V^T [B,H,64,2048]. grid (32, 24).
// BK=64 K-loop, XOR-swizzled staging (conflict-free b128 frag reads).
// Q pre-scaled by 0.125*asc[h]*log2e. V^T epilogue: LDS transpose -> b64.
__global__ __launch_bounds__(256) void gemm_qkv(
    const bf16* __restrict__ A,
    const bf16* __restrict__ Wq, const bf16* __restrict__ Wk, const bf16* __restrict__ Wv,
    const float* __restrict__ bq, const float* __restrict__ bk, const float* __restrict__ bv,
    const float* __restrict__ asc,
    bf16* __restrict__ Qb, bf16* __restrict__ Kb, bf16* __restrict__ Vtb) {
  __shared__ __align__(16) bf16 As[128 * 64];       // [row][chunk^(row&7)]
  __shared__ __align__(16) bf16 Bs[128 * 64];
  __shared__ __align__(16) bf16 scrT[4][16 * 72];   // V^T transpose scratch

  const int tid = threadIdx.x;
  const int lane = tid & 63;
  const int w = tid >> 6;
  const int m0 = blockIdx.x * 128;
  const int region = blockIdx.y >> 3;
  const int n0loc = (blockIdx.y & 7) * 128;
  const int wm = (w >> 1) * 64;
  const int wn = (w & 1) * 64;
  const int rq = lane & 15;
  const int quad = lane >> 4;

  const bf16* W = region == 0 ? Wq : (region == 1 ? Wk : Wv);
  const float* bias = region == 0 ? bq : (region == 1 ? bk : bv);
  bf16* C = region == 0 ? Qb : (region == 1 ? Kb : Vtb);

  f32x4 acc[4][4] = {};
  const bf16* Ag = A + (size_t)m0 * 1024;
  const bf16* Wg = W + (size_t)n0loc * 1024;

  const int srow = lane >> 3;                     // 0..7
  const int sws = ((lane & 7) ^ srow) * 8;        // swizzled src chunk offset
  const int c0 = (quad ^ (rq & 7)) * 8;           // frag retrieval (kstep 0)

  for (int k0 = 0; k0 < 1024; k0 += 64) {
    __syncthreads();
#pragma unroll
    for (int t = 0; t < 4; ++t) {
      int rb = w * 32 + t * 8;
      int row = rb + srow;
      async16(&As[rb * 64 + lane * 8], Ag + (size_t)row * 1024 + k0 + sws);
      async16(&Bs[rb * 64 + lane * 8], Wg + (size_t)row * 1024 + k0 + sws);
    }
    __syncthreads();

#pragma unroll
    for (int ks = 0; ks < 2; ++ks) {
      int off = c0 ^ (ks * 32);
      short8 a[4], b[4];
#pragma unroll
      for (int i = 0; i < 4; ++i) a[i] = *(const short8*)&As[(wm + i * 16 + rq) * 64 + off];
#pragma unroll
      for (int j = 0; j < 4; ++j) b[j] = *(const short8*)&Bs[(wn + j * 16 + rq) * 64 + off];
#pragma unroll
      for (int i = 0; i < 4; ++i)
#pragma unroll
        for (int j = 0; j < 4; ++j) acc[i][j] = MFMA16(a[i], b[j], acc[i][j]);
    }
  }

  const float LOG2E = 1.44269504088896f;
  if (region < 2) {
#pragma unroll
    for (int i = 0; i < 4; ++i)
#pragma unroll
      for (int j = 0; j < 4; ++j)
#pragma unroll
        for (int r2 = 0; r2 < 4; ++r2) {
          int m = m0 + wm + i * 16 + quad * 4 + r2;
          int nr = n0loc + wn + j * 16 + rq;
          int bb = m >> 11, t = m & 2047, h = nr >> 6, hd = nr & 63;
          float v = acc[i][j][r2] + bias[nr];
          if (region == 0) v *= 0.125f * asc[h] * LOG2E;
          C[(((size_t)(bb * 16 + h)) * 2048 + t) * 64 + hd] = __float2bfloat16(v);
        }
  } else {
    // V^T: per-wave transpose -> coalesced b64 stores along t
    const int bb = m0 >> 11;
    const int h = (n0loc + wn) >> 6;
    const int tbase = (m0 & 2047) + wm;
    bf16* scr = scrT[w];
#pragma unroll
    for (int j = 0; j < 4; ++j) {
      int nr = n0loc + wn + j * 16 + rq;
      float bi = bias[nr];
#pragma unroll
      for (int i = 0; i < 4; ++i) {
        short4v pv = pack4(acc[i][j][0] + bi, acc[i][j][1] + bi,
                           acc[i][j][2] + bi, acc[i][j][3] + bi);
        *(short4v*)&scr[rq * 72 + i * 16 + quad * 4] = pv;   // [dim16=rq][t64]
      }
#pragma unroll
      for (int pp = 0; pp < 4; ++pp) {
        int hdl = pp * 4 + quad;
        short4v v4 = *(const short4v*)&scr[hdl * 72 + rq * 4];
        size_t addr = (((size_t)(bb * 16 + h)) * 64 + j * 16 + hdl) * 2048 + tbase + rq * 4;
        *(short4v*)&C[addr] = v4;
      }
    }
  }
}

// Out-proj GEMM + bias + residual (fp32 out). 64x128 tile, grid (64,8) =
// 512 blocks = 2 blocks/CU — R15-proven improvement over 128x128.
__global__ __launch_bounds__(256) void gemm_out(
    const bf16* __restrict__ A, const bf16* __restrict__ W,
    const float* __restrict__ bias, const float* __restrict__ R,
    float* __restrict__ Y) {
  __shared__ __align__(16) bf16 As[64 * 64];
  __shared__ __align__(16) bf16 Bs[128 * 64];

  const int tid = threadIdx.x;
  const int lane = tid & 63;
  const int w = tid >> 6;
  const int m0 = blockIdx.x * 64;
  const int n0 = blockIdx.y * 128;
  const int wm = (w >> 1) * 32;
  const int wn = (w & 1) * 64;
  const int rq = lane & 15;
  const int quad = lane >> 4;

  f32x4 acc[2][4] = {};
  const bf16* Ag = A + (size_t)m0 * 1024;
  const bf16* Wg = W + (size_t)n0 * 1024;

  const int srow = lane >> 3;
  const int sws = ((lane & 7) ^ srow) * 8;
  const int c0 = (quad ^ (rq & 7)) * 8;

  for (int k0 = 0; k0 < 1024; k0 += 64) {
    __syncthreads();
    // A: 64 rows (wave w covers w*16..+15); B: 128 rows (w*32..+31)
#pragma unroll
    for (int t = 0; t < 2; ++t) {
      int rb = w * 16 + t * 8;
      int row = rb + srow;
      async16(&As[rb * 64 + lane * 8], Ag + (size_t)row * 1024 + k0 + sws);
    }
#pragma unroll
    for (int t = 0; t < 4; ++t) {
      int rb = w * 32 + t * 8;
      int row = rb + srow;
      async16(&Bs[rb * 64 + lane * 8], Wg + (size_t)row * 1024 + k0 + sws);
    }
    __syncthreads();

#pragma unroll
    for (int ks = 0; ks < 2; ++ks) {
      int off = c0 ^ (ks * 32);
      short8 a[2], b[4];
#pragma unroll
      for (int i = 0; i < 2; ++i) a[i] = *(const short8*)&As[(wm + i * 16 + rq) * 64 + off];
#pragma unroll
      for (int j = 0; j < 4; ++j) b[j] = *(const short8*)&Bs[(wn + j * 16 + rq) * 64 + off];
#pragma unroll
      for (int i = 0; i < 2; ++i)
#pragma unroll
        for (int j = 0; j < 4; ++j) acc[i][j] = MFMA16(a[i], b[j], acc[i][j]);
    }
  }

#pragma unroll
  for (int i = 0; i < 2; ++i)
#pragma unroll
    for (int j = 0; j < 4; ++j)
#pragma unroll
      for (int r2 = 0; r2 < 4; ++r2) {
        int m = m0 + wm + i * 16 + quad * 4 + r2;
        int n = n0 + wn + j * 16 + rq;
        Y[(size_t)m * 1024 + n] = acc[i][j][r2] + bias[n] + R[(size_t)m * 1024 + n];
      }
}

// Flash attention (R13-proven optimum): 256 threads / 4 waves, 64 q-rows/wave,
// truncating packed b64 P writes, conflict-free swizzled K/V reads, K-split x2
// + linear combine (max-free exp2 softmax, Q pre-scaled to log2 domain).
#define LP 72
__global__ __launch_bounds__(256, 2) void attn_kernel(
    const bf16* __restrict__ Qb, const bf16* __restrict__ Kb,
    const bf16* __restrict__ Vtb,
    bf16* __restrict__ P0, bf16* __restrict__ P1, float* __restrict__ lbuf) {
  __shared__ __align__(16) bf16 Ks[64 * 64];      // [key][chunk^((key>>2)&7)]
  __shared__ __align__(16) bf16 Vs[64 * 64];      // [d][chunk^(d&7)]
  __shared__ __align__(16) bf16 Ps[4][64 * LP];   // per-wave P [qrow][key]

  const int q0 = blockIdx.x * 256;
  const int h = blockIdx.y;
  const int b = blockIdx.z & 1;
  const int half = blockIdx.z >> 1;
  const int tid = threadIdx.x;
  const int lane = tid & 63;
  const int w = tid >> 6;
  const int rq = lane & 15;
  const int quad = lane >> 4;
  const int kq = quad * 8;

  const size_t head = ((size_t)(b * 16 + h)) * 2048 * 64;
  const bf16* Qh = Qb + head;
  const bf16* Kh = Kb + head;
  const bf16* Vh = Vtb + head;   // [64][2048]

  short8 aq[4][2];
#pragma unroll
  for (int s = 0; s < 4; ++s) {
    const bf16* qrow = Qh + (size_t)(q0 + w * 64 + s * 16 + rq) * 64;
    aq[s][0] = *(const short8*)&qrow[kq];
    aq[s][1] = *(const short8*)&qrow[kq + 32];
  }

  short8 ones;
#pragma unroll
  for (int i = 0; i < 8; ++i) ones[i] = (short)0x3F80;

  const int srow = lane >> 3;
  const int swsV = ((lane & 7) ^ srow) * 8;       // Vs: g=row&7
  const int c0 = (quad ^ (rq & 7)) * 8;           // bk AND bv retrieval offset
  const int c1 = c0 ^ 32;

  f32x4 accO[4][4] = {};
  f32x4 lacc[4] = {};

  const int kt0 = half * 16;
  for (int kt = kt0; kt < kt0 + 16; ++kt) {
    __syncthreads();
#pragma unroll
    for (int t = 0; t < 2; ++t) {
      int rb = w * 16 + t * 8;
      int row = rb + srow;
      int swsK = ((lane & 7) ^ ((row >> 2) & 7)) * 8;   // Ks: g=(row>>2)&7
      async16(&Ks[rb * 64 + lane * 8], Kh + (size_t)(kt * 64 + row) * 64 + swsK);
      async16(&Vs[rb * 64 + lane * 8], Vh + (size_t)row * 2048 + kt * 64 + swsV);
    }
    __syncthreads();

    short8 bk[4][2];
#pragma unroll
    for (int j = 0; j < 4; ++j) {
      const bf16* kr = &Ks[(rq * 4 + j) * 64];
      bk[j][0] = *(const short8*)&kr[c0];
      bk[j][1] = *(const short8*)&kr[c1];
    }

#pragma unroll
    for (int s = 0; s < 4; ++s) {
      f32x4 S[4] = {};
#pragma unroll
      for (int j = 0; j < 4; ++j) {
        S[j] = MFMA16(aq[s][0], bk[j][0], S[j]);
        S[j] = MFMA16(aq[s][1], bk[j][1], S[j]);
      }
#pragma unroll
      for (int r = 0; r < 4; ++r) {
        short4v pv = pack4t(exp2f(S[0][r]), exp2f(S[1][r]),
                            exp2f(S[2][r]), exp2f(S[3][r]));
        *(short4v*)&Ps[w][(s * 16 + quad * 4 + r) * LP + rq * 4] = pv;
      }
    }

    short8 bv[4][2];
#pragma unroll
    for (int dt = 0; dt < 4; ++dt) {
      const bf16* vr = &Vs[(dt * 16 + rq) * 64];
      bv[dt][0] = *(const short8*)&vr[c0];
      bv[dt][1] = *(const short8*)&vr[c1];
    }
#pragma unroll
    for (int s = 0; s < 4; ++s) {
      short8 ap0 = *(const short8*)&Ps[w][(s * 16 + rq) * LP + kq];
      short8 ap1 = *(const short8*)&Ps[w][(s * 16 + rq) * LP + kq + 32];
#pragma unroll
      for (int dt = 0; dt < 4; ++dt) {
        accO[s][dt] = MFMA16(ap0, bv[dt][0], accO[s][dt]);
        accO[s][dt] = MFMA16(ap1, bv[dt][1], accO[s][dt]);
      }
      lacc[s] = MFMA16(ap0, ones, lacc[s]);
      lacc[s] = MFMA16(ap1, ones, lacc[s]);
    }
  }

  bf16* Pout = half ? P1 : P0;
  float* lout = lbuf + half * 65536;
#pragma unroll
  for (int s = 0; s < 4; ++s) {
#pragma unroll
    for (int dt = 0; dt < 4; ++dt)
#pragma unroll
      for (int r = 0; r < 4; ++r) {
        int t = q0 + w * 64 + s * 16 + quad * 4 + r;
        int d = dt * 16 + rq;
        Pout[((size_t)(b * 2048 + t)) * 1024 + h * 64 + d] =
            __float2bfloat16(accO[s][dt][r]);
      }
    if (rq == 0) {
#pragma unroll
      for (int r = 0; r < 4; ++r) {
        int t = q0 + w * 64 + s * 16 + quad * 4 + r;
        lout[(b * 16 + h) * 2048 + t] = lacc[s][r];
      }
    }
  }
}

// Combine K-split partials: attn = (P0 + P1) / (l0 + l1)   (in-place over P0)
__global__ __launch_bounds__(256) void combine_kernel(
    bf16* __restrict__ P0, const bf16* __restrict__ P1,
    const float* __restrict__ lbuf) {
  const int row = blockIdx.x;
  const int tid = threadIdx.x;
  const int col = tid * 4;
  const int b = row >> 11, t = row & 2047;
  const int h = col >> 6;
  const float l = lbuf[(b * 16 + h) * 2048 + t] + lbuf[65536 + (b * 16 + h) * 2048 + t];
  const float rl = 1.f / l;
  size_t base = (size_t)row * 1024 + col;
  short4v p0 = *(const short4v*)&P0[base];
  short4v p1 = *(const short4v*)&P1[base];
  union { short s; bf16 h; } u;
  float v[4];
#pragma unroll
  for (int i = 0; i < 4; ++i) {
    u.s = p0[i]; float a = __bfloat162float(u.h);
    u.s = p1[i]; float c = __bfloat162float(u.h);
    v[i] = (a + c) * rl;
  }
  *(short4v*)&P0[base] = pack4(v[0], v[1], v[2], v[3]);
}

// LayerNorm over D=1024 per row; all fp32
__global__ __launch_bounds__(256) void ln_kernel(
    const float* __restrict__ Y, const float* __restrict__ gamma,
    const float* __restrict__ beta, float* __restrict__ out) {
  const int row = blockIdx.x;
  const int tid = threadIdx.x;
  const int lane = tid & 63;
  const int w = tid >> 6;
  const float* y = Y + (size_t)row * 1024;

  float4 v = *(const float4*)&y[tid * 4];
  float s = v.x + v.y + v.z + v.w;
  float ss = v.x * v.x + v.y * v.y + v.z * v.z + v.w * v.w;
#pragma unroll
  for (int msk = 1; msk < 64; msk <<= 1) {
    s += __shfl_xor(s, msk);
    ss += __shfl_xor(ss, msk);
  }
  __shared__ float red[2][4];
  if (lane == 0) { red[0][w] = s; red[1][w] = ss; }
  __syncthreads();
  s = red[0][0] + red[0][1] + red[0][2] + red[0][3];
  ss = red[1][0] + red[1][1] + red[1][2] + red[1][3];
  float mean = s * (1.f / 1024.f);
  float var = ss * (1.f / 1024.f) - mean * mean;
  float rstd = rsqrtf(var + 1e-5f);
  float4 g = *(const float4*)&gamma[tid * 4];
  float4 bt = *(const float4*)&beta[tid * 4];
  float4 o;
  o.x = (v.x - mean) * rstd * g.x + bt.x;
  o.y = (v.y - mean) * rstd * g.y + bt.y;
  o.z = (v.z - mean) * rstd * g.z + bt.z;
  o.w = (v.w - mean) * rstd * g.w + bt.w;
  *(float4*)&out[(size_t)row * 1024 + tid * 4] = o;
}

extern "C" void kernel_launch(void* const* d_in, const int* in_sizes, int n_in,
                              void* d_out, int out_size, void* d_ws, size_t ws_size,
                              hipStream_t stream) {
  const float* x     = (const float*)d_in[0];
  const float* asc   = (const float*)d_in[1];
  const float* Wq    = (const float*)d_in[2];
  const float* bq    = (const float*)d_in[3];
  const float* Wk    = (const float*)d_in[4];
  const float* bk    = (const float*)d_in[5];
  const float* Wv    = (const float*)d_in[6];
  const float* bv    = (const float*)d_in[7];
  const float* Wo    = (const float*)d_in[8];
  const float* bo    = (const float*)d_in[9];
  const float* gamma = (const float*)d_in[10];
  const float* beta  = (const float*)d_in[11];
  float* out = (float*)d_out;

  char* ws = (char*)d_ws;
  const size_t MB = 1024 * 1024;
  bf16* Qb   = (bf16*)(ws);
  bf16* Kb   = (bf16*)(ws + 8 * MB);
  bf16* Vtb  = (bf16*)(ws + 16 * MB);
  bf16* attn = (bf16*)(ws + 24 * MB);   // P0
  bf16* xb   = (bf16*)(ws + 32 * MB);   // P1 after gemm_qkv
  bf16* Wqb  = (bf16*)(ws + 40 * MB);   // lbuf after gemm_qkv
  bf16* Wkb  = (bf16*)(ws + 42 * MB);
  bf16* Wvb  = (bf16*)(ws + 44 * MB);
  bf16* Wob  = (bf16*)(ws + 46 * MB);
  float* y   = (float*)(ws);            // 16 MiB over dead Qb+Kb
  bf16* P1   = xb;
  float* lbuf = (float*)Wqb;

  cvt_all<<<dim3(8192), dim3(256), 0, stream>>>(x, Wq, Wk, Wv, Wo, xb, Wqb, Wkb, Wvb, Wob);
  gemm_qkv<<<dim3(32, 24), dim3(256), 0, stream>>>(xb, Wqb, Wkb, Wvb, bq, bk, bv, asc, Qb, Kb, Vtb);
  attn_kernel<<<dim3(8, 16, 4), dim3(256), 0, stream>>>(Qb, Kb, Vtb, attn, P1, lbuf);
  combine_kernel<<<dim3(4096), dim3(256), 0, stream>>>(attn, P1, lbuf);
  gemm_out<<<dim3(64, 8), dim3(256), 0, stream>>>(attn, Wob, bo, x, y);
  ln_kernel<<<dim3(4096), dim3(256), 0, stream>>>(y, gamma, beta, out);
}